// Round 5
// baseline (200.587 us; speedup 1.0000x reference)
//
#include <hip/hip_runtime.h>
#include <hip/hip_bf16.h>

typedef __attribute__((ext_vector_type(8))) short short8;
typedef __attribute__((ext_vector_type(16))) float f32x16;
typedef __attribute__((ext_vector_type(4))) unsigned uint4v;
typedef unsigned int u32;

#define D_DIM 128
#define G_DIM 9
#define O_DIM 128
#define K_DIM 1152
#define BROWS 256
#define INV2PI 0.15915494309189535f

__device__ __forceinline__ short f2bf(float f) {
  unsigned u = __float_as_uint(f);
  unsigned r = (u + 0x7FFFu + ((u >> 16) & 1u)) >> 16;
  return (short)r;
}

__device__ __forceinline__ unsigned pk2bf(float a, float b) {
  __hip_bfloat162 h = __float22bfloat162_rn(float2{a, b});   // v_cvt_pk_bf16_f32, a->low
  return *reinterpret_cast<unsigned*>(&h);
}

// Prep:
//  Bp (ws): 9 chunks x 128 o x 128 d bf16, row byte-swizzled: short index d ^ ((o&7)<<3)
//  pt2 (ws): [g][d] = phase[d][g] / 2pi
//  fq2 (ws): freq[g] / 2pi
__global__ void sinekan_prep(const float* __restrict__ amp,
                             const float* __restrict__ phase,
                             const float* __restrict__ freq,
                             short* __restrict__ Bp,
                             float* __restrict__ pt2,
                             float* __restrict__ fq2) {
  int i = blockIdx.x * blockDim.x + threadIdx.x;
  if (i < G_DIM * O_DIM * D_DIM) {
    int g = i >> 14, rem = i & 16383, o = rem >> 7, d = rem & 127;
    Bp[(g << 14) + (o << 7) + (d ^ ((o & 7) << 3))] = f2bf(amp[(o * D_DIM + d) * G_DIM + g]);
  }
  if (i < K_DIM) {
    int g = i >> 7, d = i & 127;
    pt2[i] = phase[d * G_DIM + g] * INV2PI;
  }
  if (i < G_DIM) fq2[i] = freq[i] * INV2PI;
}

__device__ __forceinline__ void stage_b(const short* __restrict__ Bp, short* dst_lds,
                                        int g, int tid) {
  // linear copy of pre-swizzled source; each thread copies 16B x 8 chunks
  const char* src = (const char*)Bp + ((size_t)g << 15) + tid * 16;
  char* dst = (char*)dst_lds + (tid >> 6) * 1024;
#pragma unroll
  for (int c = 0; c < 8; ++c) {
    __builtin_amdgcn_global_load_lds(
        (const __attribute__((address_space(1))) u32*)(src + c * 4096),
        (__attribute__((address_space(3))) u32*)(dst + c * 4096), 16, 0, 0);
  }
}

__global__ __launch_bounds__(256, 2)
void sinekan_fused(const float* __restrict__ x,
                   const int* __restrict__ mask,
                   const float* __restrict__ bias,
                   const float* __restrict__ lnw,
                   const float* __restrict__ lnb,
                   const short* __restrict__ Bp,
                   const float* __restrict__ pt2,
                   const float* __restrict__ fq2,
                   float* __restrict__ out) {
  __shared__ short b_lds[2][O_DIM * D_DIM];   // 2 x 32 KB, swizzled rows of 256B
  __shared__ float pt_lds[G_DIM * D_DIM];     // 4.6 KB
  __shared__ float mu_s[BROWS], rs_s[BROWS], mk_s[BROWS];
  __shared__ float w_s[D_DIM], bb_s[D_DIM];

  const int tid = threadIdx.x;
  const int row0 = blockIdx.x * BROWS;
  const int wv = tid >> 6, lane = tid & 63, lr = lane & 31, hi = lane >> 5;

  // issue B chunk 0 immediately — overlaps with init/stats
  stage_b(Bp, b_lds[0], 0, tid);

  if (tid < D_DIM) { w_s[tid] = lnw[tid]; bb_s[tid] = lnb[tid]; }
  mk_s[tid] = mask[row0 + tid] ? 1.0f : 0.0f;
  for (int i = tid; i < G_DIM * D_DIM; i += 256) pt_lds[i] = pt2[i];

  // ---- LN stats: 16 lanes per row, coalesced ----
  {
    int rloc = tid >> 4, ch = tid & 15;
#pragma unroll 1
    for (int it = 0; it < 16; ++it) {
      int r = it * 16 + rloc;
      const float4* xp = (const float4*)(x + (size_t)(row0 + r) * D_DIM + ch * 8);
      float4 a = xp[0], b = xp[1];
      float s  = a.x + a.y + a.z + a.w + b.x + b.y + b.z + b.w;
      float sq = a.x*a.x + a.y*a.y + a.z*a.z + a.w*a.w
               + b.x*b.x + b.y*b.y + b.z*b.z + b.w*b.w;
#pragma unroll
      for (int off = 1; off < 16; off <<= 1) {
        s  += __shfl_xor(s, off, 64);
        sq += __shfl_xor(sq, off, 64);
      }
      if (ch == 0) {
        float m = s * (1.0f / 128.0f);
        mu_s[r] = m;
        rs_s[r] = rsqrtf(sq * (1.0f / 128.0f) - m * m + 1e-5f);
      }
    }
  }
  __syncthreads();   // stats ready (also drains part of stage(0))

  // ---- cache xn (LN output incl. weight/bias) as packed bf16: 64 VGPR ----
  uint4v xnc[2][8];
#pragma unroll
  for (int m = 0; m < 2; ++m) {
    const int rl = wv * 64 + m * 32 + lr;
    const float mu = mu_s[rl], rs = rs_s[rl];
    const float* xr = x + (size_t)(row0 + rl) * D_DIM;
#pragma unroll
    for (int kk = 0; kk < 8; ++kk) {
      const int d0 = kk * 16 + hi * 8;
      float4 xa = *(const float4*)(xr + d0);
      float4 xb = *(const float4*)(xr + d0 + 4);
      float xv[8] = {xa.x, xa.y, xa.z, xa.w, xb.x, xb.y, xb.z, xb.w};
      uint4v pk;
#pragma unroll
      for (int jj = 0; jj < 4; ++jj) {
        float e0 = (xv[2*jj]   - mu) * rs * w_s[d0 + 2*jj]   + bb_s[d0 + 2*jj];
        float e1 = (xv[2*jj+1] - mu) * rs * w_s[d0 + 2*jj+1] + bb_s[d0 + 2*jj+1];
        pk[jj] = pk2bf(e0, e1);
      }
      xnc[m][kk] = pk;
    }
  }
  __syncthreads();   // b_lds[0] staged & drained

  // per-lane hoisted addressing
  const int hs = ((hi << 4) ^ ((lr & 7) << 4));             // XOR key, bits 4..6
  const char* blr = (const char*)&b_lds[0][0] + (lr << 8);  // + (g&1)*32KB + n*8KB + ((kk<<5)^hs)
  const float* ptl = pt_lds + (hi << 3);                    // + g*128 + kk*16

  f32x16 acc[2][4] = {};

#pragma unroll 1
  for (int g = 0; g < G_DIM; ++g) {
    if (g + 1 < G_DIM) stage_b(Bp, b_lds[(g + 1) & 1], g + 1, tid);  // flies under kk-loop
    const float fgv = fq2[g];
    const char* bl = blr + ((g & 1) << 15);   // 32KB buffer stride (R4 bug: was <<16)
    const float* ptg = ptl + (g << 7);

#pragma unroll
    for (int kk = 0; kk < 8; ++kk) {
      // ---- issue all loads FIRST: their latency hides under the sine VALU below ----
      const char* ba = bl + (((kk << 5)) ^ hs);
      short8 bf0 = *(const short8*)(ba);
      short8 bf1 = *(const short8*)(ba + 8192);
      short8 bf2 = *(const short8*)(ba + 16384);
      short8 bf3 = *(const short8*)(ba + 24576);
      float4 p0 = *(const float4*)(ptg + kk * 16);
      float4 p1 = *(const float4*)(ptg + kk * 16 + 4);

      // ---- A-fragments: unpack + fma + v_sin + cvt_pk (independent VALU chain) ----
      const float ph[8] = {p0.x, p0.y, p0.z, p0.w, p1.x, p1.y, p1.z, p1.w};
      short8 af[2];
#pragma unroll
      for (int m = 0; m < 2; ++m) {
        uint4v pk;
#pragma unroll
        for (int jj = 0; jj < 4; ++jj) {
          unsigned u = xnc[m][kk][jj];
          float e0 = __uint_as_float(u << 16);
          float e1 = __uint_as_float(u & 0xffff0000u);
          float s0 = __builtin_amdgcn_sinf(fmaf(e0, fgv, ph[2*jj]));
          float s1 = __builtin_amdgcn_sinf(fmaf(e1, fgv, ph[2*jj+1]));
          pk[jj] = pk2bf(s0, s1);
        }
        af[m] = __builtin_bit_cast(short8, pk);
      }

      __builtin_amdgcn_s_setprio(1);
      acc[0][0] = __builtin_amdgcn_mfma_f32_32x32x16_bf16(af[0], bf0, acc[0][0], 0, 0, 0);
      acc[0][1] = __builtin_amdgcn_mfma_f32_32x32x16_bf16(af[0], bf1, acc[0][1], 0, 0, 0);
      acc[0][2] = __builtin_amdgcn_mfma_f32_32x32x16_bf16(af[0], bf2, acc[0][2], 0, 0, 0);
      acc[0][3] = __builtin_amdgcn_mfma_f32_32x32x16_bf16(af[0], bf3, acc[0][3], 0, 0, 0);
      acc[1][0] = __builtin_amdgcn_mfma_f32_32x32x16_bf16(af[1], bf0, acc[1][0], 0, 0, 0);
      acc[1][1] = __builtin_amdgcn_mfma_f32_32x32x16_bf16(af[1], bf1, acc[1][1], 0, 0, 0);
      acc[1][2] = __builtin_amdgcn_mfma_f32_32x32x16_bf16(af[1], bf2, acc[1][2], 0, 0, 0);
      acc[1][3] = __builtin_amdgcn_mfma_f32_32x32x16_bf16(af[1], bf3, acc[1][3], 0, 0, 0);
      __builtin_amdgcn_s_setprio(0);
    }
    __syncthreads();  // drains stage(g+1); b_lds[g&1] free for g+2
  }

  // ---- epilogue: + bias, * mask ----
#pragma unroll
  for (int m = 0; m < 2; ++m) {
#pragma unroll
    for (int n = 0; n < 4; ++n) {
      int col = n * 32 + lr;
      float bv = bias[col];
#pragma unroll
      for (int reg = 0; reg < 16; ++reg) {
        int rit  = (reg & 3) + 8 * (reg >> 2) + 4 * hi;
        int rloc = wv * 64 + m * 32 + rit;
        out[(size_t)(row0 + rloc) * O_DIM + col] = (acc[m][n][reg] + bv) * mk_s[rloc];
      }
    }
  }
}

extern "C" void kernel_launch(void* const* d_in, const int* in_sizes, int n_in,
                              void* d_out, int out_size, void* d_ws, size_t ws_size,
                              hipStream_t stream) {
  const float* x    = (const float*)d_in[0];
  const int* mk     = (const int*)d_in[1];
  const float* freq = (const float*)d_in[2];
  const float* phase= (const float*)d_in[3];
  const float* amp  = (const float*)d_in[4];
  const float* bias = (const float*)d_in[5];
  const float* lnw  = (const float*)d_in[6];
  const float* lnb  = (const float*)d_in[7];
  float* out = (float*)d_out;

  int N = in_sizes[0] / D_DIM;                 // 131072 rows
  short* Bp = (short*)d_ws;                    // 294912 B swizzled bf16
  float* pt2 = (float*)((char*)d_ws + (size_t)G_DIM * O_DIM * D_DIM * sizeof(short));
  float* fq2 = pt2 + G_DIM * D_DIM;

  int total = G_DIM * O_DIM * D_DIM;           // 147456
  sinekan_prep<<<(total + 255) / 256, 256, 0, stream>>>(amp, phase, freq, Bp, pt2, fq2);
  sinekan_fused<<<N / BROWS, 256, 0, stream>>>(x, mk, bias, lnw, lnb, Bp, pt2, fq2, out);
}

// Round 6
// 184.412 us; speedup vs baseline: 1.0877x; 1.0877x over previous
//
#include <hip/hip_runtime.h>
#include <hip/hip_bf16.h>

typedef __attribute__((ext_vector_type(8))) short short8;
typedef __attribute__((ext_vector_type(16))) float f32x16;
typedef __attribute__((ext_vector_type(4))) unsigned uint4v;
typedef unsigned int u32;

#define D_DIM 128
#define G_DIM 9
#define O_DIM 128
#define K_DIM 1152
#define BROWS 256
#define NTHR 512
#define INV2PI 0.15915494309189535f

__device__ __forceinline__ short f2bf(float f) {
  unsigned u = __float_as_uint(f);
  unsigned r = (u + 0x7FFFu + ((u >> 16) & 1u)) >> 16;
  return (short)r;
}

__device__ __forceinline__ unsigned pk2bf(float a, float b) {
  __hip_bfloat162 h = __float22bfloat162_rn(float2{a, b});   // v_cvt_pk_bf16_f32, a->low
  return *reinterpret_cast<unsigned*>(&h);
}

// Prep:
//  Bp (ws): 9 chunks x 128 o x 128 d bf16, row byte-swizzled: short index d ^ ((o&7)<<3)
//  pt2 (ws): [g][d] = phase[d][g] / 2pi
//  fq2 (ws): freq[g] / 2pi
__global__ void sinekan_prep(const float* __restrict__ amp,
                             const float* __restrict__ phase,
                             const float* __restrict__ freq,
                             short* __restrict__ Bp,
                             float* __restrict__ pt2,
                             float* __restrict__ fq2) {
  int i = blockIdx.x * blockDim.x + threadIdx.x;
  if (i < G_DIM * O_DIM * D_DIM) {
    int g = i >> 14, rem = i & 16383, o = rem >> 7, d = rem & 127;
    Bp[(g << 14) + (o << 7) + (d ^ ((o & 7) << 3))] = f2bf(amp[(o * D_DIM + d) * G_DIM + g]);
  }
  if (i < K_DIM) {
    int g = i >> 7, d = i & 127;
    pt2[i] = phase[d * G_DIM + g] * INV2PI;
  }
  if (i < G_DIM) fq2[i] = freq[i] * INV2PI;
}

__device__ __forceinline__ void stage_b(const short* __restrict__ Bp, short* dst_lds,
                                        int g, int tid) {
  // linear copy of pre-swizzled source; 512 threads x 16B x 4 chunks = 32 KB
  const char* src = (const char*)Bp + ((size_t)g << 15) + tid * 16;
  char* dst = (char*)dst_lds + (tid >> 6) * 1024;
#pragma unroll
  for (int c = 0; c < 4; ++c) {
    __builtin_amdgcn_global_load_lds(
        (const __attribute__((address_space(1))) u32*)(src + c * 8192),
        (__attribute__((address_space(3))) u32*)(dst + c * 8192), 16, 0, 0);
  }
}

__global__ __launch_bounds__(NTHR, 3)
void sinekan_fused(const float* __restrict__ x,
                   const int* __restrict__ mask,
                   const float* __restrict__ bias,
                   const float* __restrict__ lnw,
                   const float* __restrict__ lnb,
                   const short* __restrict__ Bp,
                   const float* __restrict__ pt2,
                   const float* __restrict__ fq2,
                   float* __restrict__ out) {
  __shared__ short b_lds[2][O_DIM * D_DIM];   // 2 x 32 KB, swizzled rows of 256B
  __shared__ float pt_lds[G_DIM * D_DIM];     // 4.6 KB
  __shared__ float mu_s[BROWS], rs_s[BROWS], mk_s[BROWS];
  __shared__ float w_s[D_DIM], bb_s[D_DIM];

  const int tid = threadIdx.x;
  const int row0 = blockIdx.x * BROWS;
  const int wv = tid >> 6, lane = tid & 63, lr = lane & 31, hi = lane >> 5;

  // issue B chunk 0 immediately — overlaps with init/stats
  stage_b(Bp, b_lds[0], 0, tid);

  if (tid < D_DIM) { w_s[tid] = lnw[tid]; bb_s[tid] = lnb[tid]; }
  if (tid < BROWS) mk_s[tid] = mask[row0 + tid] ? 1.0f : 0.0f;
  for (int i = tid; i < G_DIM * D_DIM; i += NTHR) pt_lds[i] = pt2[i];

  // ---- LN stats: 16 lanes per row, coalesced; 8 iters x 32 rows ----
  {
    int rloc = tid >> 4, ch = tid & 15;
#pragma unroll 1
    for (int it = 0; it < 8; ++it) {
      int r = it * 32 + rloc;
      const float4* xp = (const float4*)(x + (size_t)(row0 + r) * D_DIM + ch * 8);
      float4 a = xp[0], b = xp[1];
      float s  = a.x + a.y + a.z + a.w + b.x + b.y + b.z + b.w;
      float sq = a.x*a.x + a.y*a.y + a.z*a.z + a.w*a.w
               + b.x*b.x + b.y*b.y + b.z*b.z + b.w*b.w;
#pragma unroll
      for (int off = 1; off < 16; off <<= 1) {
        s  += __shfl_xor(s, off, 64);
        sq += __shfl_xor(sq, off, 64);
      }
      if (ch == 0) {
        float m = s * (1.0f / 128.0f);
        mu_s[r] = m;
        rs_s[r] = rsqrtf(sq * (1.0f / 128.0f) - m * m + 1e-5f);
      }
    }
  }
  __syncthreads();   // stats ready; also drains stage(0) -> b_lds[0] valid

  // ---- cache xn (LN output incl. weight/bias) as packed bf16: 32 VGPR ----
  // wave owns rows wv*32..wv*32+31; lane covers row (wv*32+lr), d-half hi
  uint4v xnc[8];
  {
    const int rl = wv * 32 + lr;
    const float mu = mu_s[rl], rs = rs_s[rl];
    const float* xr = x + (size_t)(row0 + rl) * D_DIM;
#pragma unroll
    for (int kk = 0; kk < 8; ++kk) {
      const int d0 = kk * 16 + hi * 8;
      float4 xa = *(const float4*)(xr + d0);
      float4 xb = *(const float4*)(xr + d0 + 4);
      float xv[8] = {xa.x, xa.y, xa.z, xa.w, xb.x, xb.y, xb.z, xb.w};
      uint4v pk;
#pragma unroll
      for (int jj = 0; jj < 4; ++jj) {
        float e0 = (xv[2*jj]   - mu) * rs * w_s[d0 + 2*jj]   + bb_s[d0 + 2*jj];
        float e1 = (xv[2*jj+1] - mu) * rs * w_s[d0 + 2*jj+1] + bb_s[d0 + 2*jj+1];
        pk[jj] = pk2bf(e0, e1);
      }
      xnc[kk] = pk;
    }
  }

  // per-lane hoisted addressing
  const int hs = (hi << 4) ^ ((lr & 7) << 4);               // XOR key, bits 4..6
  const char* blr = (const char*)&b_lds[0][0] + (lr << 8);  // + (g&1)*32KB + n*8KB + ((kk<<5)^hs)
  const float* ptl = pt_lds + (hi << 3);                    // + g*128 + kk*16

  f32x16 acc[4] = {};

#pragma unroll 1
  for (int g = 0; g < G_DIM; ++g) {
    if (g + 1 < G_DIM) stage_b(Bp, b_lds[(g + 1) & 1], g + 1, tid);  // flies under kk-loop
    const float fgv = fq2[g];
    const char* bl = blr + ((g & 1) << 15);   // 32KB buffer stride
    const float* ptg = ptl + (g << 7);

    // preload phase slice for kk=0
    float4 p0 = *(const float4*)(ptg);
    float4 p1 = *(const float4*)(ptg + 4);

#pragma unroll
    for (int kk = 0; kk < 8; ++kk) {
      // b-frags issued first: latency hides under the sine chain
      const char* ba = bl + ((kk << 5) ^ hs);
      short8 bf0 = *(const short8*)(ba);
      short8 bf1 = *(const short8*)(ba + 8192);
      short8 bf2 = *(const short8*)(ba + 16384);
      short8 bf3 = *(const short8*)(ba + 24576);
      // software-pipelined phase load for kk+1 (consumed next iter; hides under MFMA)
      const int kn = (kk + 1) & 7;
      float4 q0 = *(const float4*)(ptg + kn * 16);
      float4 q1 = *(const float4*)(ptg + kn * 16 + 4);

      // A-fragment: unpack + fma + v_sin + cvt_pk (ph already in regs -> no head stall)
      const float ph[8] = {p0.x, p0.y, p0.z, p0.w, p1.x, p1.y, p1.z, p1.w};
      uint4v pk;
#pragma unroll
      for (int jj = 0; jj < 4; ++jj) {
        unsigned u = xnc[kk][jj];
        float s0 = __builtin_amdgcn_sinf(fmaf(__uint_as_float(u << 16),         fgv, ph[2*jj]));
        float s1 = __builtin_amdgcn_sinf(fmaf(__uint_as_float(u & 0xffff0000u), fgv, ph[2*jj+1]));
        pk[jj] = pk2bf(s0, s1);
      }
      short8 af = __builtin_bit_cast(short8, pk);

      __builtin_amdgcn_s_setprio(1);
      acc[0] = __builtin_amdgcn_mfma_f32_32x32x16_bf16(af, bf0, acc[0], 0, 0, 0);
      acc[1] = __builtin_amdgcn_mfma_f32_32x32x16_bf16(af, bf1, acc[1], 0, 0, 0);
      acc[2] = __builtin_amdgcn_mfma_f32_32x32x16_bf16(af, bf2, acc[2], 0, 0, 0);
      acc[3] = __builtin_amdgcn_mfma_f32_32x32x16_bf16(af, bf3, acc[3], 0, 0, 0);
      __builtin_amdgcn_s_setprio(0);

      p0 = q0; p1 = q1;
    }
    __syncthreads();  // drains stage(g+1); b_lds[g&1] free for g+2
  }

  // ---- epilogue: + bias, * mask ----
#pragma unroll
  for (int n = 0; n < 4; ++n) {
    int col = n * 32 + lr;
    float bv = bias[col];
#pragma unroll
    for (int reg = 0; reg < 16; ++reg) {
      int rit  = (reg & 3) + 8 * (reg >> 2) + 4 * hi;
      int rloc = wv * 32 + rit;
      out[(size_t)(row0 + rloc) * O_DIM + col] = (acc[n][reg] + bv) * mk_s[rloc];
    }
  }
}

extern "C" void kernel_launch(void* const* d_in, const int* in_sizes, int n_in,
                              void* d_out, int out_size, void* d_ws, size_t ws_size,
                              hipStream_t stream) {
  const float* x    = (const float*)d_in[0];
  const int* mk     = (const int*)d_in[1];
  const float* freq = (const float*)d_in[2];
  const float* phase= (const float*)d_in[3];
  const float* amp  = (const float*)d_in[4];
  const float* bias = (const float*)d_in[5];
  const float* lnw  = (const float*)d_in[6];
  const float* lnb  = (const float*)d_in[7];
  float* out = (float*)d_out;

  int N = in_sizes[0] / D_DIM;                 // 131072 rows
  short* Bp = (short*)d_ws;                    // 294912 B swizzled bf16
  float* pt2 = (float*)((char*)d_ws + (size_t)G_DIM * O_DIM * D_DIM * sizeof(short));
  float* fq2 = pt2 + G_DIM * D_DIM;

  int total = G_DIM * O_DIM * D_DIM;           // 147456
  sinekan_prep<<<(total + 255) / 256, 256, 0, stream>>>(amp, phase, freq, Bp, pt2, fq2);
  sinekan_fused<<<N / BROWS, NTHR, 0, stream>>>(x, mk, bias, lnw, lnb, Bp, pt2, fq2, out);
}